// Round 8
// baseline (76.837 us; speedup 1.0000x reference)
//
#include <hip/hip_runtime.h>

// Bahdanau additive attention, MI355X.  B=8, TE=TD=256, HE=HD=512.
// d_in (f32): enc [B,TE,H], dec [B,TD,H], W_a [H,H], U_a [H,H], V_a [H,1]
// d_out (f32): c [B,TD,H] | e [B,TD,TE]
//
// Math: tanh(x) = 1 - 2/(1+e^{2x}).  score = Sv - 2*A,
// A[d,t] = sum_k Va[k]/(1 + EW[t,k]*EU[d,k]),  EW = exp2(2log2e * enc@Wa), EU likewise.
// Sv const over t -> dropped (softmax shift invariance); softmax over min(A),
// -2 folded into the exp2 constant.
//
// R8: occupancy pass. score k-split 8 -> 1024 blocks (4 waves/SIMD);
// ctx h-quarters -> 512 blocks; proj reg-prefetch pipeline.
// ws (~27MB): WTa .5M | WTu .5M | encT 2M | EW 4M | EU 4M | Apart 8x2M

#define BB  8
#define TEE 256
#define TDD 256
#define HH  512
#define C2LOG2E 2.8853900817779268f   // 2*log2(e)
#define SLAB ((size_t)BB * TDD * TEE)
#define NKS 8                          // k-split slices

typedef __attribute__((ext_vector_type(8))) short  short8;
typedef __attribute__((ext_vector_type(4))) float  floatx4;

__device__ __forceinline__ unsigned short f2bf(float f) {
  unsigned int u = __builtin_bit_cast(unsigned int, f);
  u += 0x7FFFu + ((u >> 16) & 1u);            // RNE
  return (unsigned short)(u >> 16);
}

// ---------- prep: WT[n][k]=bf16(W[k][n]*2log2e); encT[b][h][t]=bf16(enc[b][t][h]) ----------
__global__ __launch_bounds__(256) void prep_kernel(
    const float* __restrict__ Wa, const float* __restrict__ Ua,
    const float* __restrict__ enc,
    unsigned short* __restrict__ WTa, unsigned short* __restrict__ WTu,
    unsigned short* __restrict__ encT)
{
  __shared__ float tile[64][65];
  const int c = threadIdx.x & 63, r4 = threadIdx.x >> 6;
  const int z = blockIdx.z;

  if (z < 2) {
    const float* W = z ? Ua : Wa;
    unsigned short* WT = z ? WTu : WTa;
    const int k0 = blockIdx.x * 64, n0 = blockIdx.y * 64;
    #pragma unroll
    for (int i = 0; i < 16; ++i) {
      int kr = i * 4 + r4;
      tile[kr][c] = W[(size_t)(k0 + kr) * HH + n0 + c];
    }
    __syncthreads();
    #pragma unroll
    for (int i = 0; i < 16; ++i) {
      int nr = i * 4 + r4;
      WT[(size_t)(n0 + nr) * HH + k0 + c] = f2bf(tile[c][nr] * C2LOG2E);
    }
  } else {
    if (blockIdx.y >= 4) return;
    const int b = z - 2;
    const int h0 = blockIdx.x * 64, t0 = blockIdx.y * 64;
    #pragma unroll
    for (int i = 0; i < 16; ++i) {
      int tr = i * 4 + r4;
      tile[tr][c] = enc[((size_t)b * TEE + t0 + tr) * HH + h0 + c];
    }
    __syncthreads();
    #pragma unroll
    for (int i = 0; i < 16; ++i) {
      int hr = i * 4 + r4;
      encT[((size_t)b * HH + h0 + hr) * TEE + t0 + c] = f2bf(tile[c][hr]);
    }
  }
}

// ---------- phase 1: EW = exp2(X @ WT^T), bf16 MFMA, reg-prefetch pipeline ----------
// grid (32, 8, 2), block 256 = 4 waves; wave w: rows m0+w*16.., cols n0..n0+64.
__global__ __launch_bounds__(256) void proj_exp(
    const float* __restrict__ enc, const float* __restrict__ dec,
    const unsigned short* __restrict__ WTa, const unsigned short* __restrict__ WTu,
    float* __restrict__ EW, float* __restrict__ EU)
{
  const float* X = blockIdx.z ? dec : enc;
  const unsigned short* WT = blockIdx.z ? WTu : WTa;
  float* Y = blockIdx.z ? EU : EW;
  const int lane = threadIdx.x & 63, w = threadIdx.x >> 6;
  const int m0 = blockIdx.x * 64 + w * 16, n0 = blockIdx.y * 64;
  const int r15 = lane & 15, g = lane >> 4;

  floatx4 acc0 = {0.f,0.f,0.f,0.f}, acc1 = {0.f,0.f,0.f,0.f};
  floatx4 acc2 = {0.f,0.f,0.f,0.f}, acc3 = {0.f,0.f,0.f,0.f};
  const float* ap = X + (size_t)(m0 + r15) * HH + g * 8;
  const unsigned short* bp0 = WT + (size_t)(n0 + r15) * HH + g * 8;

  float4 ca0 = *(const float4*)(ap);
  float4 ca1 = *(const float4*)(ap + 4);
  short8 cb0 = *(const short8*)(bp0);
  short8 cb1 = *(const short8*)(bp0 + (size_t)16 * HH);
  short8 cb2 = *(const short8*)(bp0 + (size_t)32 * HH);
  short8 cb3 = *(const short8*)(bp0 + (size_t)48 * HH);

  for (int k0 = 0; k0 < HH; k0 += 32) {
    float4 na0, na1; short8 nb0, nb1, nb2, nb3;
    if (k0 + 32 < HH) {                         // prefetch next chunk
      na0 = *(const float4*)(ap + k0 + 32);
      na1 = *(const float4*)(ap + k0 + 36);
      nb0 = *(const short8*)(bp0 + k0 + 32);
      nb1 = *(const short8*)(bp0 + (size_t)16 * HH + k0 + 32);
      nb2 = *(const short8*)(bp0 + (size_t)32 * HH + k0 + 32);
      nb3 = *(const short8*)(bp0 + (size_t)48 * HH + k0 + 32);
    }
    short8 a;
    a[0]=(short)f2bf(ca0.x); a[1]=(short)f2bf(ca0.y);
    a[2]=(short)f2bf(ca0.z); a[3]=(short)f2bf(ca0.w);
    a[4]=(short)f2bf(ca1.x); a[5]=(short)f2bf(ca1.y);
    a[6]=(short)f2bf(ca1.z); a[7]=(short)f2bf(ca1.w);
    acc0 = __builtin_amdgcn_mfma_f32_16x16x32_bf16(a, cb0, acc0, 0, 0, 0);
    acc1 = __builtin_amdgcn_mfma_f32_16x16x32_bf16(a, cb1, acc1, 0, 0, 0);
    acc2 = __builtin_amdgcn_mfma_f32_16x16x32_bf16(a, cb2, acc2, 0, 0, 0);
    acc3 = __builtin_amdgcn_mfma_f32_16x16x32_bf16(a, cb3, acc3, 0, 0, 0);
    ca0 = na0; ca1 = na1; cb0 = nb0; cb1 = nb1; cb2 = nb2; cb3 = nb3;
  }
  // D: col = lane&15, row = (lane>>4)*4 + reg  [m89-verified]
  floatx4 aall[4] = {acc0, acc1, acc2, acc3};
  #pragma unroll
  for (int nt = 0; nt < 4; ++nt) {
    float* yp = Y + (size_t)(m0 + g * 4) * HH + n0 + nt * 16 + r15;
    #pragma unroll
    for (int r = 0; r < 4; ++r) {
      float v = fminf(fmaxf(aall[nt][r], -126.f), 126.f);  // finite & nonzero
      yp[(size_t)r * HH] = __builtin_amdgcn_exp2f(v);
    }
  }
}

// ---------- phase 2: Apart[ks][b,d,t] = sum_{k slice of 64} Va[k]*rcp(1+EW*EU) ----------
// 64t x 64d tile, 4x4/thread, k-split 8, double-buffered LDS, 1 barrier/chunk.
// grid (32 = 4 t-tiles x 8 ks, 4 d-tiles, 8 b), block 256 -> 1024 blocks, 4 blk/CU.
__global__ __launch_bounds__(256) void score_rt(
    const float* __restrict__ EW, const float* __restrict__ EU,
    const float* __restrict__ Va, float* __restrict__ Apart)
{
  __shared__ float swT[2][32][68];   // [buf][k][t], pad 68 -> 2-way banks (free)
  __shared__ float suT[2][32][68];   // [buf][k][d]

  const int b  = blockIdx.z;
  const int ks = blockIdx.x >> 2;            // k-slice 0..7 (64 k each)
  const int t0 = (blockIdx.x & 3) * 64;
  const int d0 = blockIdx.y * 64;
  const int kbase = ks * 64;
  const int tid = threadIdx.x;
  const int tx = tid & 15, ty = tid >> 4;    // thread -> 4t x 4d
  const int sr = tid >> 2, fq = tid & 3;     // staging: row 0..63, quad 0..3
  const int kq = fq * 4;

  const float* wsrc = EW + ((size_t)(b * TEE) + t0 + sr) * HH + kbase + kq;
  const float* usrc = EU + ((size_t)(b * TDD) + d0 + sr) * HH + kbase + kq;

  float acc[4][4] = {};   // [d j][t i]

#define STAGE(BUF_, W0_, W1_, U0_, U1_) {                         \
    swT[BUF_][kq + 0][sr] = W0_.x; swT[BUF_][kq + 1][sr] = W0_.y; \
    swT[BUF_][kq + 2][sr] = W0_.z; swT[BUF_][kq + 3][sr] = W0_.w; \
    swT[BUF_][kq +16][sr] = W1_.x; swT[BUF_][kq +17][sr] = W1_.y; \
    swT[BUF_][kq +18][sr] = W1_.z; swT[BUF_][kq +19][sr] = W1_.w; \
    suT[BUF_][kq + 0][sr] = U0_.x; suT[BUF_][kq + 1][sr] = U0_.y; \
    suT[BUF_][kq + 2][sr] = U0_.z; suT[BUF_][kq + 3][sr] = U0_.w; \
    suT[BUF_][kq +16][sr] = U1_.x; suT[BUF_][kq +17][sr] = U1_.y; \
    suT[BUF_][kq +18][sr] = U1_.z; suT[BUF_][kq +19][sr] = U1_.w; }

  {   // prologue: chunk 0 -> buf 0
    float4 w0 = *(const float4*)(wsrc);
    float4 w1 = *(const float4*)(wsrc + 16);
    float4 u0 = *(const float4*)(usrc);
    float4 u1 = *(const float4*)(usrc + 16);
    STAGE(0, w0, w1, u0, u1)
  }

  for (int ch = 0; ch < 2; ++ch) {           // 2 chunks of 32 k
    float4 nw0, nw1, nu0, nu1;
    const bool more = (ch == 0);
    if (more) {                              // prefetch next chunk into regs
      nw0 = *(const float4*)(wsrc + 32);
      nw1 = *(const float4*)(wsrc + 48);
      nu0 = *(const float4*)(usrc + 32);
      nu1 = *(const float4*)(usrc + 48);
    }
    __syncthreads();                         // buf[ch] writes visible

    const float* vb = Va + kbase + ch * 32;
#define T1(WI_, UJ_, AJI_) { \
    float z_ = fmaf((WI_), (UJ_), 1.0f); \
    AJI_ = fmaf(v, __builtin_amdgcn_rcpf(z_), AJI_); }

    #pragma unroll 4
    for (int k = 0; k < 32; ++k) {
      floatx4 w = *(const floatx4*)&swT[ch][k][tx * 4];
      floatx4 u = *(const floatx4*)&suT[ch][k][ty * 4];
      float v = vb[k];                       // uniform -> s_load
      #pragma unroll
      for (int j = 0; j < 4; ++j) {
        float uj = u[j];
        T1(w[0], uj, acc[j][0]) T1(w[1], uj, acc[j][1])
        T1(w[2], uj, acc[j][2]) T1(w[3], uj, acc[j][3])
      }
    }
#undef T1

    if (more) STAGE(1, nw0, nw1, nu0, nu1)   // other buf: no hazard
  }
#undef STAGE

  float* Ap = Apart + (size_t)ks * SLAB;
  #pragma unroll
  for (int j = 0; j < 4; ++j) {
    const int d = d0 + ty * 4 + j;
    floatx4 o = {acc[j][0], acc[j][1], acc[j][2], acc[j][3]};
    *(floatx4*)(Ap + ((size_t)(b * TDD) + d) * TEE + t0 + tx * 4) = o;
  }
}

// ---------- phase 3+4 fused: softmax(sum Apart) -> e; c = e @ enc (bf16 MFMA) ----------
// grid (16 d-tiles of 16, 4 h-quarters of 128, 8 b) = 512 blocks, block 256 = 4 waves.
__global__ __launch_bounds__(256) void ctx_fused(
    const float* __restrict__ Apart, const unsigned short* __restrict__ encT,
    float* __restrict__ c, float* __restrict__ e_out)
{
  __shared__ unsigned short pe[16][264];

  const int b  = blockIdx.z;
  const int d0 = blockIdx.x * 16;
  const int h0 = blockIdx.y * 128;
  const int lane = threadIdx.x & 63, w = threadIdx.x >> 6;

  // --- softmax: wave w owns rows w*4 + (lane>>4); 16 lanes/row, 16 cols/lane
  {
    const int row  = w * 4 + (lane >> 4);
    const int col0 = (lane & 15) * 16;
    const size_t base = ((size_t)(b * TDD) + d0 + row) * TEE + col0;
    float x[16];
    #pragma unroll
    for (int q = 0; q < 4; ++q) {
      floatx4 v = *(const floatx4*)(Apart + base + q * 4);
      x[4*q] = v[0]; x[4*q+1] = v[1]; x[4*q+2] = v[2]; x[4*q+3] = v[3];
    }
    #pragma unroll
    for (int s = 1; s < NKS; ++s) {
      #pragma unroll
      for (int q = 0; q < 4; ++q) {
        floatx4 v = *(const floatx4*)(Apart + (size_t)s * SLAB + base + q * 4);
        x[4*q] += v[0]; x[4*q+1] += v[1]; x[4*q+2] += v[2]; x[4*q+3] += v[3];
      }
    }
    float m = x[0];
    #pragma unroll
    for (int j = 1; j < 16; ++j) m = fminf(m, x[j]);
    #pragma unroll
    for (int off = 8; off; off >>= 1) m = fminf(m, __shfl_xor(m, off)); // 16-lane grp
    float p[16], s = 0.f;
    #pragma unroll
    for (int j = 0; j < 16; ++j) {
      p[j] = __builtin_amdgcn_exp2f(C2LOG2E * (m - x[j]));
      s += p[j];
    }
    #pragma unroll
    for (int off = 8; off; off >>= 1) s += __shfl_xor(s, off);
    float r = __builtin_amdgcn_rcpf(s);

    #pragma unroll
    for (int j = 0; j < 16; j += 2) {
      float v0 = p[j] * r, v1 = p[j+1] * r;
      *(ushort2*)&pe[row][col0 + j] = make_ushort2(f2bf(v0), f2bf(v1));
    }
    if (blockIdx.y == 0) {
      float* er = e_out + ((size_t)(b * TDD) + d0 + row) * TEE + col0;
      #pragma unroll
      for (int j = 0; j < 16; ++j) er[j] = p[j] * r;
    }
  }
  __syncthreads();

  // --- MFMA: wave w covers h = h0 + w*32 .. +32 (2 col-tiles)
  const int r15 = lane & 15, g = lane >> 4;
  const int hw = h0 + w * 32;
  floatx4 acc0 = {0.f,0.f,0.f,0.f}, acc1 = {0.f,0.f,0.f,0.f};
  const unsigned short* bp0 = encT + ((size_t)b * HH + hw + r15) * TEE + g * 8;

  for (int k0 = 0; k0 < TEE; k0 += 32) {
    short8 a = *(const short8*)(&pe[r15][k0 + g * 8]);
    short8 bv0 = *(const short8*)(bp0 + k0);
    short8 bv1 = *(const short8*)(bp0 + (size_t)16 * TEE + k0);
    acc0 = __builtin_amdgcn_mfma_f32_16x16x32_bf16(a, bv0, acc0, 0, 0, 0);
    acc1 = __builtin_amdgcn_mfma_f32_16x16x32_bf16(a, bv1, acc1, 0, 0, 0);
  }
  floatx4 aall[2] = {acc0, acc1};
  #pragma unroll
  for (int nt = 0; nt < 2; ++nt) {
    float* cp = c + ((size_t)(b * TDD) + d0 + g * 4) * HH + hw + nt * 16 + r15;
    #pragma unroll
    for (int r = 0; r < 4; ++r) cp[(size_t)r * HH] = aall[nt][r];
  }
}

extern "C" void kernel_launch(void* const* d_in, const int* in_sizes, int n_in,
                              void* d_out, int out_size, void* d_ws, size_t ws_size,
                              hipStream_t stream) {
  const float* enc = (const float*)d_in[0];
  const float* dec = (const float*)d_in[1];
  const float* Wa  = (const float*)d_in[2];
  const float* Ua  = (const float*)d_in[3];
  const float* Va  = (const float*)d_in[4];

  float* c_out = (float*)d_out;                          // f32 c [B*TD*H]
  float* e_out = c_out + (size_t)BB * TDD * HH;          // f32 e [B*TD*TE]

  unsigned short* WTa  = (unsigned short*)d_ws;          // bf16 512KB
  unsigned short* WTu  = WTa + (size_t)HH * HH;          // bf16 512KB
  unsigned short* encT = WTu + (size_t)HH * HH;          // bf16 2MB
  float* EW    = (float*)(encT + (size_t)BB * HH * TEE); // f32 4MB
  float* EU    = EW + (size_t)BB * TEE * HH;             // f32 4MB
  float* Apart = EU + (size_t)BB * TDD * HH;             // f32 8 x 2MB

  prep_kernel<<<dim3(8, 8, 10),  256, 0, stream>>>(Wa, Ua, enc, WTa, WTu, encT);
  proj_exp   <<<dim3(32, 8, 2),  256, 0, stream>>>(enc, dec, WTa, WTu, EW, EU);
  score_rt   <<<dim3(32, 4, 8),  256, 0, stream>>>(EW, EU, Va, Apart);
  ctx_fused  <<<dim3(16, 4, 8),  256, 0, stream>>>(Apart, encT, c_out, e_out);
}

// Round 9
// 63.231 us; speedup vs baseline: 1.2152x; 1.2152x over previous
//
#include <hip/hip_runtime.h>

// Bahdanau additive attention, MI355X.  B=8, TE=TD=256, HE=HD=512.
// d_in (f32): enc [B,TE,H], dec [B,TD,H], W_a [H,H], U_a [H,H], V_a [H,1]
// d_out (f32): c [B,TD,H] | e [B,TD,TE]
//
// Math: tanh(x) = 1 - 2/(1+e^{2x}).  score = Sv - 2*A,
// A[d,t] = sum_k Va[k]/(1 + EW[t,k]*EU[d,k]),  EW = exp2(clamp(2log2e*enc@Wa,±31)).
// Sv const over t -> dropped; softmax over min(A), -2 folded into exp2 const.
// R9: pairwise rcp  v1/(1+a)+v2/(1+b) = (v1(1+b)+v2(1+a))/((1+a)(1+b))
//     -> one v_rcp per TWO k-elements (halves trans-pipe work).
//     prep merged into proj launch (W read strided, encT as extra blocks): 3 kernels.
// ws (~26MB): encT 2M | EW 4M | EU 4M | Apart 8x2M

#define BB  8
#define TEE 256
#define TDD 256
#define HH  512
#define C2LOG2E 2.8853900817779268f   // 2*log2(e)
#define SLAB ((size_t)BB * TDD * TEE)
#define NKS 8                          // k-split slices

typedef __attribute__((ext_vector_type(8))) short  short8;
typedef __attribute__((ext_vector_type(4))) float  floatx4;

__device__ __forceinline__ unsigned short f2bf(float f) {
  unsigned int u = __builtin_bit_cast(unsigned int, f);
  u += 0x7FFFu + ((u >> 16) & 1u);            // RNE
  return (unsigned short)(u >> 16);
}

// ---------- kernel 1: proj (EW, EU) + encT transpose, one launch ----------
// blocks 0..255: EW; 256..511: EU; 512..767: encT.  block 256 thr = 4 waves.
__global__ __launch_bounds__(256) void proj_all(
    const float* __restrict__ enc, const float* __restrict__ dec,
    const float* __restrict__ Wa,  const float* __restrict__ Ua,
    float* __restrict__ EW, float* __restrict__ EU,
    unsigned short* __restrict__ encT)
{
  __shared__ float tile[64][65];
  const int bid = blockIdx.x;

  if (bid < 512) {
    const int side = bid >> 8;               // 0 = EW, 1 = EU
    const int lb = bid & 255;
    const float* X = side ? dec : enc;
    const float* W = side ? Ua  : Wa;
    float*       Y = side ? EU  : EW;
    const int lane = threadIdx.x & 63, w = threadIdx.x >> 6;
    const int m0 = (lb >> 3) * 64 + w * 16;  // 32 m-tiles of 64, wave picks 16
    const int n0 = (lb & 7) * 64;
    const int r15 = lane & 15, g = lane >> 4;

    floatx4 acc[4] = {{0.f,0.f,0.f,0.f},{0.f,0.f,0.f,0.f},
                      {0.f,0.f,0.f,0.f},{0.f,0.f,0.f,0.f}};
    const float* ap = X + (size_t)(m0 + r15) * HH + g * 8;

    for (int k0 = 0; k0 < HH; k0 += 32) {
      float4 a0 = *(const float4*)(ap + k0);
      float4 a1 = *(const float4*)(ap + k0 + 4);
      short8 a;                                 // scale folded into A side
      a[0]=(short)f2bf(a0.x*C2LOG2E); a[1]=(short)f2bf(a0.y*C2LOG2E);
      a[2]=(short)f2bf(a0.z*C2LOG2E); a[3]=(short)f2bf(a0.w*C2LOG2E);
      a[4]=(short)f2bf(a1.x*C2LOG2E); a[5]=(short)f2bf(a1.y*C2LOG2E);
      a[6]=(short)f2bf(a1.z*C2LOG2E); a[7]=(short)f2bf(a1.w*C2LOG2E);
      const float* wrow = W + (size_t)(k0 + g * 8) * HH + n0 + r15;
      #pragma unroll
      for (int nt = 0; nt < 4; ++nt) {
        short8 bv;                              // strided W reads, f2bf
        #pragma unroll
        for (int j = 0; j < 8; ++j) bv[j] = (short)f2bf(wrow[(size_t)j * HH + nt * 16]);
        acc[nt] = __builtin_amdgcn_mfma_f32_16x16x32_bf16(a, bv, acc[nt], 0, 0, 0);
      }
    }
    // D: col = lane&15, row = (lane>>4)*4 + reg  [m89-verified]
    #pragma unroll
    for (int nt = 0; nt < 4; ++nt) {
      float* yp = Y + (size_t)(m0 + g * 4) * HH + n0 + nt * 16 + r15;
      #pragma unroll
      for (int r = 0; r < 4; ++r) {
        float v = fminf(fmaxf(acc[nt][r], -31.f), 31.f);  // keep all products finite
        yp[(size_t)r * HH] = __builtin_amdgcn_exp2f(v);
      }
    }
  } else {
    // encT[b][h][t] = bf16(enc[b][t][h]);  256 blocks: 8 b x 8 h-tiles x 4 t-tiles
    const int idx = bid - 512;
    const int b  = idx >> 5;
    const int h0 = ((idx >> 2) & 7) * 64;
    const int t0 = (idx & 3) * 64;
    const int c = threadIdx.x & 63, r4 = threadIdx.x >> 6;
    #pragma unroll
    for (int i = 0; i < 16; ++i) {
      int tr = i * 4 + r4;
      tile[tr][c] = enc[((size_t)b * TEE + t0 + tr) * HH + h0 + c];
    }
    __syncthreads();
    #pragma unroll
    for (int i = 0; i < 16; ++i) {
      int hr = i * 4 + r4;
      encT[((size_t)b * HH + h0 + hr) * TEE + t0 + c] = f2bf(tile[c][hr]);
    }
  }
}

// ---------- kernel 2: Apart[ks][b,d,t] = sum_{k slice of 64} Va[k]*rcp(1+EW*EU) ----------
// 64t x 64d tile, 4x4/thread, k-split 8, dbuf LDS, PAIRWISE rcp (1 rcp / 2 k).
// grid (32 = 4 t-tiles x 8 ks, 4 d-tiles, 8 b), block 256 -> 1024 blocks.
__global__ __launch_bounds__(256) void score_rt(
    const float* __restrict__ EW, const float* __restrict__ EU,
    const float* __restrict__ Va, float* __restrict__ Apart)
{
  __shared__ float swT[2][32][68];   // [buf][k][t]
  __shared__ float suT[2][32][68];   // [buf][k][d]

  const int b  = blockIdx.z;
  const int ks = blockIdx.x >> 2;            // k-slice 0..7 (64 k each)
  const int t0 = (blockIdx.x & 3) * 64;
  const int d0 = blockIdx.y * 64;
  const int kbase = ks * 64;
  const int tid = threadIdx.x;
  const int tx = tid & 15, ty = tid >> 4;    // thread -> 4t x 4d
  const int sr = tid >> 2, fq = tid & 3;     // staging: row 0..63, quad 0..3
  const int kq = fq * 4;

  const float* wsrc = EW + ((size_t)(b * TEE) + t0 + sr) * HH + kbase + kq;
  const float* usrc = EU + ((size_t)(b * TDD) + d0 + sr) * HH + kbase + kq;

  float acc[4][4] = {};   // [d j][t i]

#define STAGE(BUF_, W0_, W1_, U0_, U1_) {                         \
    swT[BUF_][kq + 0][sr] = W0_.x; swT[BUF_][kq + 1][sr] = W0_.y; \
    swT[BUF_][kq + 2][sr] = W0_.z; swT[BUF_][kq + 3][sr] = W0_.w; \
    swT[BUF_][kq +16][sr] = W1_.x; swT[BUF_][kq +17][sr] = W1_.y; \
    swT[BUF_][kq +18][sr] = W1_.z; swT[BUF_][kq +19][sr] = W1_.w; \
    suT[BUF_][kq + 0][sr] = U0_.x; suT[BUF_][kq + 1][sr] = U0_.y; \
    suT[BUF_][kq + 2][sr] = U0_.z; suT[BUF_][kq + 3][sr] = U0_.w; \
    suT[BUF_][kq +16][sr] = U1_.x; suT[BUF_][kq +17][sr] = U1_.y; \
    suT[BUF_][kq +18][sr] = U1_.z; suT[BUF_][kq +19][sr] = U1_.w; }

  {   // prologue: chunk 0 -> buf 0
    float4 w0 = *(const float4*)(wsrc);
    float4 w1 = *(const float4*)(wsrc + 16);
    float4 u0 = *(const float4*)(usrc);
    float4 u1 = *(const float4*)(usrc + 16);
    STAGE(0, w0, w1, u0, u1)
  }

  for (int ch = 0; ch < 2; ++ch) {           // 2 chunks of 32 k
    float4 nw0, nw1, nu0, nu1;
    const bool more = (ch == 0);
    if (more) {                              // prefetch next chunk into regs
      nw0 = *(const float4*)(wsrc + 32);
      nw1 = *(const float4*)(wsrc + 48);
      nu0 = *(const float4*)(usrc + 32);
      nu1 = *(const float4*)(usrc + 48);
    }
    __syncthreads();                         // buf[ch] writes visible

    const float* vb = Va + kbase + ch * 32;

    // pairwise: v1/(1+a) + v2/(1+b) = (v1*(1+b)+v2*(1+a)) * rcp((1+a)*(1+b))
    #pragma unroll 4
    for (int kk = 0; kk < 32; kk += 2) {
      floatx4 wA = *(const floatx4*)&swT[ch][kk    ][tx * 4];
      floatx4 wB = *(const floatx4*)&swT[ch][kk + 1][tx * 4];
      floatx4 uA = *(const floatx4*)&suT[ch][kk    ][ty * 4];
      floatx4 uB = *(const floatx4*)&suT[ch][kk + 1][ty * 4];
      float2 vv = *(const float2*)(vb + kk);   // uniform -> s_load
      const float v1 = vv.x, v2 = vv.y;
      #pragma unroll
      for (int j = 0; j < 4; ++j) {
        float u1 = uA[j], u2 = uB[j];
        #pragma unroll
        for (int i = 0; i < 4; ++i) {
          float a  = wA[i] * u1;               // EW(k)*EU(k)
          float bq = wB[i] * u2;               // EW(k+1)*EU(k+1)
          float A1 = 1.0f + a;
          float B1 = 1.0f + bq;
          float den = A1 * B1;
          float num = fmaf(v1, B1, v2 * A1);
          acc[j][i] = fmaf(num, __builtin_amdgcn_rcpf(den), acc[j][i]);
        }
      }
    }

    if (more) STAGE(1, nw0, nw1, nu0, nu1)   // other buf: no hazard
  }
#undef STAGE

  float* Ap = Apart + (size_t)ks * SLAB;
  #pragma unroll
  for (int j = 0; j < 4; ++j) {
    const int d = d0 + ty * 4 + j;
    floatx4 o = {acc[j][0], acc[j][1], acc[j][2], acc[j][3]};
    *(floatx4*)(Ap + ((size_t)(b * TDD) + d) * TEE + t0 + tx * 4) = o;
  }
}

// ---------- kernel 3: softmax(sum Apart) -> e; c = e @ enc (bf16 MFMA) ----------
// grid (16 d-tiles of 16, 4 h-quarters of 128, 8 b) = 512 blocks, block 256 = 4 waves.
__global__ __launch_bounds__(256) void ctx_fused(
    const float* __restrict__ Apart, const unsigned short* __restrict__ encT,
    float* __restrict__ c, float* __restrict__ e_out)
{
  __shared__ unsigned short pe[16][264];

  const int b  = blockIdx.z;
  const int d0 = blockIdx.x * 16;
  const int h0 = blockIdx.y * 128;
  const int lane = threadIdx.x & 63, w = threadIdx.x >> 6;

  // --- softmax: wave w owns rows w*4 + (lane>>4); 16 lanes/row, 16 cols/lane
  {
    const int row  = w * 4 + (lane >> 4);
    const int col0 = (lane & 15) * 16;
    const size_t base = ((size_t)(b * TDD) + d0 + row) * TEE + col0;
    float x[16];
    #pragma unroll
    for (int q = 0; q < 4; ++q) {
      floatx4 v = *(const floatx4*)(Apart + base + q * 4);
      x[4*q] = v[0]; x[4*q+1] = v[1]; x[4*q+2] = v[2]; x[4*q+3] = v[3];
    }
    #pragma unroll
    for (int s = 1; s < NKS; ++s) {
      #pragma unroll
      for (int q = 0; q < 4; ++q) {
        floatx4 v = *(const floatx4*)(Apart + (size_t)s * SLAB + base + q * 4);
        x[4*q] += v[0]; x[4*q+1] += v[1]; x[4*q+2] += v[2]; x[4*q+3] += v[3];
      }
    }
    float m = x[0];
    #pragma unroll
    for (int j = 1; j < 16; ++j) m = fminf(m, x[j]);
    #pragma unroll
    for (int off = 8; off; off >>= 1) m = fminf(m, __shfl_xor(m, off)); // 16-lane grp
    float p[16], s = 0.f;
    #pragma unroll
    for (int j = 0; j < 16; ++j) {
      p[j] = __builtin_amdgcn_exp2f(C2LOG2E * (m - x[j]));
      s += p[j];
    }
    #pragma unroll
    for (int off = 8; off; off >>= 1) s += __shfl_xor(s, off);
    float r = __builtin_amdgcn_rcpf(s);

    #pragma unroll
    for (int j = 0; j < 16; j += 2) {
      float v0 = p[j] * r, v1 = p[j+1] * r;
      *(ushort2*)&pe[row][col0 + j] = make_ushort2(f2bf(v0), f2bf(v1));
    }
    if (blockIdx.y == 0) {
      float* er = e_out + ((size_t)(b * TDD) + d0 + row) * TEE + col0;
      #pragma unroll
      for (int j = 0; j < 16; ++j) er[j] = p[j] * r;
    }
  }
  __syncthreads();

  // --- MFMA: wave w covers h = h0 + w*32 .. +32 (2 col-tiles)
  const int r15 = lane & 15, g = lane >> 4;
  const int hw = h0 + w * 32;
  floatx4 acc0 = {0.f,0.f,0.f,0.f}, acc1 = {0.f,0.f,0.f,0.f};
  const unsigned short* bp0 = encT + ((size_t)b * HH + hw + r15) * TEE + g * 8;

  for (int k0 = 0; k0 < TEE; k0 += 32) {
    short8 a = *(const short8*)(&pe[r15][k0 + g * 8]);
    short8 bv0 = *(const short8*)(bp0 + k0);
    short8 bv1 = *(const short8*)(bp0 + (size_t)16 * TEE + k0);
    acc0 = __builtin_amdgcn_mfma_f32_16x16x32_bf16(a, bv0, acc0, 0, 0, 0);
    acc1 = __builtin_amdgcn_mfma_f32_16x16x32_bf16(a, bv1, acc1, 0, 0, 0);
  }
  floatx4 aall[2] = {acc0, acc1};
  #pragma unroll
  for (int nt = 0; nt < 2; ++nt) {
    float* cp = c + ((size_t)(b * TDD) + d0 + g * 4) * HH + hw + nt * 16 + r15;
    #pragma unroll
    for (int r = 0; r < 4; ++r) cp[(size_t)r * HH] = aall[nt][r];
  }
}

extern "C" void kernel_launch(void* const* d_in, const int* in_sizes, int n_in,
                              void* d_out, int out_size, void* d_ws, size_t ws_size,
                              hipStream_t stream) {
  const float* enc = (const float*)d_in[0];
  const float* dec = (const float*)d_in[1];
  const float* Wa  = (const float*)d_in[2];
  const float* Ua  = (const float*)d_in[3];
  const float* Va  = (const float*)d_in[4];

  float* c_out = (float*)d_out;                          // f32 c [B*TD*H]
  float* e_out = c_out + (size_t)BB * TDD * HH;          // f32 e [B*TD*TE]

  unsigned short* encT = (unsigned short*)d_ws;          // bf16 2MB
  float* EW    = (float*)(encT + (size_t)BB * HH * TEE); // f32 4MB
  float* EU    = EW + (size_t)BB * TEE * HH;             // f32 4MB
  float* Apart = EU + (size_t)BB * TDD * HH;             // f32 8 x 2MB

  proj_all  <<<768,              256, 0, stream>>>(enc, dec, Wa, Ua, EW, EU, encT);
  score_rt  <<<dim3(32, 4, 8),   256, 0, stream>>>(EW, EU, Va, Apart);
  ctx_fused <<<dim3(16, 4, 8),   256, 0, stream>>>(Apart, encT, c_out, e_out);
}

// Round 10
// 60.904 us; speedup vs baseline: 1.2616x; 1.0382x over previous
//
#include <hip/hip_runtime.h>
#include <hip/hip_bf16.h>

// Bahdanau additive attention, MI355X.  B=8, TE=TD=256, HE=HD=512.
// d_in (f32): enc [B,TE,H], dec [B,TD,H], W_a [H,H], U_a [H,H], V_a [H,1]
// d_out (f32): c [B,TD,H] | e [B,TD,TE]
//
// Math: tanh(x) = 1 - 2/(1+e^{2x}).  score = Sv - 2*A,
// A[d,t] = sum_k Va[k]/(1 + EW[t,k]*EU[d,k]),  EW = exp2(clamp(2log2e*enc@Wa,±15)).
// Sv const over t -> dropped; softmax over min(A), -2 folded into exp2 const.
// R10: 4-way rcp tree (1 v_rcp / 4 k-elements; clamp ±15 keeps den4 <= 2^120 finite)
//      + native __float2bfloat16 (compiler emits v_cvt_pk_bf16_f32, 2 elems/inst).
// ws (~26MB): encT 2M | EW 4M | EU 4M | Apart 8x2M

#define BB  8
#define TEE 256
#define TDD 256
#define HH  512
#define C2LOG2E 2.8853900817779268f   // 2*log2(e)
#define SLAB ((size_t)BB * TDD * TEE)
#define NKS 8                          // k-split slices

typedef __attribute__((ext_vector_type(8))) short  short8;
typedef __attribute__((ext_vector_type(4))) float  floatx4;

__device__ __forceinline__ unsigned short f2bf(float f) {
  __hip_bfloat16 h = __float2bfloat16(f);      // RNE; compiler packs into cvt_pk
  return __builtin_bit_cast(unsigned short, h);
}

// ---------- kernel 1: proj (EW, EU) + encT transpose, one launch ----------
// blocks 0..255: EW; 256..511: EU; 512..767: encT.  block 256 thr = 4 waves.
__global__ __launch_bounds__(256) void proj_all(
    const float* __restrict__ enc, const float* __restrict__ dec,
    const float* __restrict__ Wa,  const float* __restrict__ Ua,
    float* __restrict__ EW, float* __restrict__ EU,
    unsigned short* __restrict__ encT)
{
  __shared__ float tile[64][65];
  const int bid = blockIdx.x;

  if (bid < 512) {
    const int side = bid >> 8;               // 0 = EW, 1 = EU
    const int lb = bid & 255;
    const float* X = side ? dec : enc;
    const float* W = side ? Ua  : Wa;
    float*       Y = side ? EU  : EW;
    const int lane = threadIdx.x & 63, w = threadIdx.x >> 6;
    const int m0 = (lb >> 3) * 64 + w * 16;  // 32 m-tiles of 64, wave picks 16
    const int n0 = (lb & 7) * 64;
    const int r15 = lane & 15, g = lane >> 4;

    floatx4 acc[4] = {{0.f,0.f,0.f,0.f},{0.f,0.f,0.f,0.f},
                      {0.f,0.f,0.f,0.f},{0.f,0.f,0.f,0.f}};
    const float* ap = X + (size_t)(m0 + r15) * HH + g * 8;

    for (int k0 = 0; k0 < HH; k0 += 32) {
      float4 a0 = *(const float4*)(ap + k0);
      float4 a1 = *(const float4*)(ap + k0 + 4);
      short8 a;                                 // scale folded into A side
      a[0]=(short)f2bf(a0.x*C2LOG2E); a[1]=(short)f2bf(a0.y*C2LOG2E);
      a[2]=(short)f2bf(a0.z*C2LOG2E); a[3]=(short)f2bf(a0.w*C2LOG2E);
      a[4]=(short)f2bf(a1.x*C2LOG2E); a[5]=(short)f2bf(a1.y*C2LOG2E);
      a[6]=(short)f2bf(a1.z*C2LOG2E); a[7]=(short)f2bf(a1.w*C2LOG2E);
      const float* wrow = W + (size_t)(k0 + g * 8) * HH + n0 + r15;
      #pragma unroll
      for (int nt = 0; nt < 4; ++nt) {
        short8 bv;                              // strided W reads, native cvt
        #pragma unroll
        for (int j = 0; j < 8; ++j) bv[j] = (short)f2bf(wrow[(size_t)j * HH + nt * 16]);
        acc[nt] = __builtin_amdgcn_mfma_f32_16x16x32_bf16(a, bv, acc[nt], 0, 0, 0);
      }
    }
    // D: col = lane&15, row = (lane>>4)*4 + reg  [m89-verified]
    #pragma unroll
    for (int nt = 0; nt < 4; ++nt) {
      float* yp = Y + (size_t)(m0 + g * 4) * HH + n0 + nt * 16 + r15;
      #pragma unroll
      for (int r = 0; r < 4; ++r) {
        float v = fminf(fmaxf(acc[nt][r], -15.f), 15.f);  // den4 stays finite
        yp[(size_t)r * HH] = __builtin_amdgcn_exp2f(v);
      }
    }
  } else {
    // encT[b][h][t] = bf16(enc[b][t][h]);  256 blocks: 8 b x 8 h-tiles x 4 t-tiles
    const int idx = bid - 512;
    const int b  = idx >> 5;
    const int h0 = ((idx >> 2) & 7) * 64;
    const int t0 = (idx & 3) * 64;
    const int c = threadIdx.x & 63, r4 = threadIdx.x >> 6;
    #pragma unroll
    for (int i = 0; i < 16; ++i) {
      int tr = i * 4 + r4;
      tile[tr][c] = enc[((size_t)b * TEE + t0 + tr) * HH + h0 + c];
    }
    __syncthreads();
    #pragma unroll
    for (int i = 0; i < 16; ++i) {
      int hr = i * 4 + r4;
      encT[((size_t)b * HH + h0 + hr) * TEE + t0 + c] = f2bf(tile[c][hr]);
    }
  }
}

// ---------- kernel 2: Apart[ks][b,d,t] = sum_{k slice of 64} Va[k]/(1+EW*EU) ----------
// 64t x 64d tile, 4x4/thread, k-split 8, dbuf LDS, 4-WAY rcp tree (1 rcp / 4 k).
// grid (32 = 4 t-tiles x 8 ks, 4 d-tiles, 8 b), block 256 -> 1024 blocks.
__global__ __launch_bounds__(256) void score_rt(
    const float* __restrict__ EW, const float* __restrict__ EU,
    const float* __restrict__ Va, float* __restrict__ Apart)
{
  __shared__ float swT[2][32][68];   // [buf][k][t]
  __shared__ float suT[2][32][68];   // [buf][k][d]

  const int b  = blockIdx.z;
  const int ks = blockIdx.x >> 2;            // k-slice 0..7 (64 k each)
  const int t0 = (blockIdx.x & 3) * 64;
  const int d0 = blockIdx.y * 64;
  const int kbase = ks * 64;
  const int tid = threadIdx.x;
  const int tx = tid & 15, ty = tid >> 4;    // thread -> 4t x 4d
  const int sr = tid >> 2, fq = tid & 3;     // staging: row 0..63, quad 0..3
  const int kq = fq * 4;

  const float* wsrc = EW + ((size_t)(b * TEE) + t0 + sr) * HH + kbase + kq;
  const float* usrc = EU + ((size_t)(b * TDD) + d0 + sr) * HH + kbase + kq;

  float acc[4][4] = {};   // [d j][t i]

#define STAGE(BUF_, W0_, W1_, U0_, U1_) {                         \
    swT[BUF_][kq + 0][sr] = W0_.x; swT[BUF_][kq + 1][sr] = W0_.y; \
    swT[BUF_][kq + 2][sr] = W0_.z; swT[BUF_][kq + 3][sr] = W0_.w; \
    swT[BUF_][kq +16][sr] = W1_.x; swT[BUF_][kq +17][sr] = W1_.y; \
    swT[BUF_][kq +18][sr] = W1_.z; swT[BUF_][kq +19][sr] = W1_.w; \
    suT[BUF_][kq + 0][sr] = U0_.x; suT[BUF_][kq + 1][sr] = U0_.y; \
    suT[BUF_][kq + 2][sr] = U0_.z; suT[BUF_][kq + 3][sr] = U0_.w; \
    suT[BUF_][kq +16][sr] = U1_.x; suT[BUF_][kq +17][sr] = U1_.y; \
    suT[BUF_][kq +18][sr] = U1_.z; suT[BUF_][kq +19][sr] = U1_.w; }

  {   // prologue: chunk 0 -> buf 0
    float4 w0 = *(const float4*)(wsrc);
    float4 w1 = *(const float4*)(wsrc + 16);
    float4 u0 = *(const float4*)(usrc);
    float4 u1 = *(const float4*)(usrc + 16);
    STAGE(0, w0, w1, u0, u1)
  }

  for (int ch = 0; ch < 2; ++ch) {           // 2 chunks of 32 k
    float4 nw0, nw1, nu0, nu1;
    const bool more = (ch == 0);
    if (more) {                              // prefetch next chunk into regs
      nw0 = *(const float4*)(wsrc + 32);
      nw1 = *(const float4*)(wsrc + 48);
      nu0 = *(const float4*)(usrc + 32);
      nu1 = *(const float4*)(usrc + 48);
    }
    __syncthreads();                         // buf[ch] writes visible

    const float* vb = Va + kbase + ch * 32;

    // 4-way tree: leaves (num=v_i, den=1+a_i); combine (n,d),(n',d') ->
    //   den = d*d', num = n*d' + n'*d;  one rcp per 4 k.
    #pragma unroll 2
    for (int kk = 0; kk < 32; kk += 4) {
      floatx4 wA = *(const floatx4*)&swT[ch][kk    ][tx * 4];
      floatx4 wB = *(const floatx4*)&swT[ch][kk + 1][tx * 4];
      floatx4 wC = *(const floatx4*)&swT[ch][kk + 2][tx * 4];
      floatx4 wD = *(const floatx4*)&swT[ch][kk + 3][tx * 4];
      floatx4 uA = *(const floatx4*)&suT[ch][kk    ][ty * 4];
      floatx4 uB = *(const floatx4*)&suT[ch][kk + 1][ty * 4];
      floatx4 uC = *(const floatx4*)&suT[ch][kk + 2][ty * 4];
      floatx4 uD = *(const floatx4*)&suT[ch][kk + 3][ty * 4];
      float4 vv = *(const float4*)(vb + kk);   // uniform -> s_load
      #pragma unroll
      for (int j = 0; j < 4; ++j) {
        float u1 = uA[j], u2 = uB[j], u3 = uC[j], u4 = uD[j];
        #pragma unroll
        for (int i = 0; i < 4; ++i) {
          float A1 = fmaf(wA[i], u1, 1.0f);
          float B1 = fmaf(wB[i], u2, 1.0f);
          float C1 = fmaf(wC[i], u3, 1.0f);
          float D1 = fmaf(wD[i], u4, 1.0f);
          float dab = A1 * B1;
          float nab = fmaf(vv.x, B1, vv.y * A1);
          float dcd = C1 * D1;
          float ncd = fmaf(vv.z, D1, vv.w * C1);
          float den = dab * dcd;
          float num = fmaf(nab, dcd, ncd * dab);
          acc[j][i] = fmaf(num, __builtin_amdgcn_rcpf(den), acc[j][i]);
        }
      }
    }

    if (more) STAGE(1, nw0, nw1, nu0, nu1)   // other buf: no hazard
  }
#undef STAGE

  float* Ap = Apart + (size_t)ks * SLAB;
  #pragma unroll
  for (int j = 0; j < 4; ++j) {
    const int d = d0 + ty * 4 + j;
    floatx4 o = {acc[j][0], acc[j][1], acc[j][2], acc[j][3]};
    *(floatx4*)(Ap + ((size_t)(b * TDD) + d) * TEE + t0 + tx * 4) = o;
  }
}

// ---------- kernel 3: softmax(sum Apart) -> e; c = e @ enc (bf16 MFMA) ----------
// grid (16 d-tiles of 16, 4 h-quarters of 128, 8 b) = 512 blocks, block 256 = 4 waves.
__global__ __launch_bounds__(256) void ctx_fused(
    const float* __restrict__ Apart, const unsigned short* __restrict__ encT,
    float* __restrict__ c, float* __restrict__ e_out)
{
  __shared__ unsigned short pe[16][264];

  const int b  = blockIdx.z;
  const int d0 = blockIdx.x * 16;
  const int h0 = blockIdx.y * 128;
  const int lane = threadIdx.x & 63, w = threadIdx.x >> 6;

  // --- softmax: wave w owns rows w*4 + (lane>>4); 16 lanes/row, 16 cols/lane
  {
    const int row  = w * 4 + (lane >> 4);
    const int col0 = (lane & 15) * 16;
    const size_t base = ((size_t)(b * TDD) + d0 + row) * TEE + col0;
    float x[16];
    #pragma unroll
    for (int q = 0; q < 4; ++q) {
      floatx4 v = *(const floatx4*)(Apart + base + q * 4);
      x[4*q] = v[0]; x[4*q+1] = v[1]; x[4*q+2] = v[2]; x[4*q+3] = v[3];
    }
    #pragma unroll
    for (int s = 1; s < NKS; ++s) {
      #pragma unroll
      for (int q = 0; q < 4; ++q) {
        floatx4 v = *(const floatx4*)(Apart + (size_t)s * SLAB + base + q * 4);
        x[4*q] += v[0]; x[4*q+1] += v[1]; x[4*q+2] += v[2]; x[4*q+3] += v[3];
      }
    }
    float m = x[0];
    #pragma unroll
    for (int j = 1; j < 16; ++j) m = fminf(m, x[j]);
    #pragma unroll
    for (int off = 8; off; off >>= 1) m = fminf(m, __shfl_xor(m, off)); // 16-lane grp
    float p[16], s = 0.f;
    #pragma unroll
    for (int j = 0; j < 16; ++j) {
      p[j] = __builtin_amdgcn_exp2f(C2LOG2E * (m - x[j]));
      s += p[j];
    }
    #pragma unroll
    for (int off = 8; off; off >>= 1) s += __shfl_xor(s, off);
    float r = __builtin_amdgcn_rcpf(s);

    #pragma unroll
    for (int j = 0; j < 16; j += 2) {
      float v0 = p[j] * r, v1 = p[j+1] * r;
      *(ushort2*)&pe[row][col0 + j] = make_ushort2(f2bf(v0), f2bf(v1));
    }
    if (blockIdx.y == 0) {
      float* er = e_out + ((size_t)(b * TDD) + d0 + row) * TEE + col0;
      #pragma unroll
      for (int j = 0; j < 16; ++j) er[j] = p[j] * r;
    }
  }
  __syncthreads();

  // --- MFMA: wave w covers h = h0 + w*32 .. +32 (2 col-tiles)
  const int r15 = lane & 15, g = lane >> 4;
  const int hw = h0 + w * 32;
  floatx4 acc0 = {0.f,0.f,0.f,0.f}, acc1 = {0.f,0.f,0.f,0.f};
  const unsigned short* bp0 = encT + ((size_t)b * HH + hw + r15) * TEE + g * 8;

  for (int k0 = 0; k0 < TEE; k0 += 32) {
    short8 a = *(const short8*)(&pe[r15][k0 + g * 8]);
    short8 bv0 = *(const short8*)(bp0 + k0);
    short8 bv1 = *(const short8*)(bp0 + (size_t)16 * TEE + k0);
    acc0 = __builtin_amdgcn_mfma_f32_16x16x32_bf16(a, bv0, acc0, 0, 0, 0);
    acc1 = __builtin_amdgcn_mfma_f32_16x16x32_bf16(a, bv1, acc1, 0, 0, 0);
  }
  floatx4 aall[2] = {acc0, acc1};
  #pragma unroll
  for (int nt = 0; nt < 2; ++nt) {
    float* cp = c + ((size_t)(b * TDD) + d0 + g * 4) * HH + hw + nt * 16 + r15;
    #pragma unroll
    for (int r = 0; r < 4; ++r) cp[(size_t)r * HH] = aall[nt][r];
  }
}

extern "C" void kernel_launch(void* const* d_in, const int* in_sizes, int n_in,
                              void* d_out, int out_size, void* d_ws, size_t ws_size,
                              hipStream_t stream) {
  const float* enc = (const float*)d_in[0];
  const float* dec = (const float*)d_in[1];
  const float* Wa  = (const float*)d_in[2];
  const float* Ua  = (const float*)d_in[3];
  const float* Va  = (const float*)d_in[4];

  float* c_out = (float*)d_out;                          // f32 c [B*TD*H]
  float* e_out = c_out + (size_t)BB * TDD * HH;          // f32 e [B*TD*TE]

  unsigned short* encT = (unsigned short*)d_ws;          // bf16 2MB
  float* EW    = (float*)(encT + (size_t)BB * HH * TEE); // f32 4MB
  float* EU    = EW + (size_t)BB * TEE * HH;             // f32 4MB
  float* Apart = EU + (size_t)BB * TDD * HH;             // f32 8 x 2MB

  proj_all  <<<768,              256, 0, stream>>>(enc, dec, Wa, Ua, EW, EU, encT);
  score_rt  <<<dim3(32, 4, 8),   256, 0, stream>>>(EW, EU, Va, Apart);
  ctx_fused <<<dim3(16, 4, 8),   256, 0, stream>>>(Apart, encT, c_out, e_out);
}